// Round 1
// baseline (930.890 us; speedup 1.0000x reference)
//
#include <hip/hip_runtime.h>

// MlpWithAttention: B=2^20 rows, in=64, H=32, out=64, fp32.
// Attention over T=1 => softmax==1 => affine fold: h <- h@(I+g*wv) + g*bv,
// folded into the preceding Linear (preproc). Main kernel: one thread = one row,
// float2-packed math (v_pk_fma_f32) throughout, weights via wave-uniform s_load.
// This version: LDS-staged coalesced global I/O (16-col chunks, stride-18 pad),
// 18.4 KB LDS -> 8 blocks/CU, 8 waves/EU requested.

#define HDIM 32
#define EPS 1e-5f
#define SLOPE 0.01f

typedef float v2f __attribute__((ext_vector_type(2)));

// ws layout (floats):
//   0    .. 2048 : W1f[64][32]  (k-major, j contiguous)
//   2048 .. 2080 : B1f[32]
//   2080 .. 3104 : W2f[32][32]  (k-major)
//   3104 .. 3136 : B2f[32]

__global__ void mlp_preproc(
    const float* __restrict__ w1, const float* __restrict__ b1,
    const float* __restrict__ wv1, const float* __restrict__ bv1,
    const float* __restrict__ g1,
    const float* __restrict__ w2, const float* __restrict__ b2,
    const float* __restrict__ wv2, const float* __restrict__ bv2,
    const float* __restrict__ g2,
    float* __restrict__ ws)
{
    const int t = threadIdx.x;  // one block, 256 threads
    const float gg1 = g1[0], gg2 = g2[0];

    // W1f = w1 + g1*(w1@wv1)   [64x32]
    for (int e = t; e < 64 * HDIM; e += 256) {
        int k = e >> 5, j = e & 31;
        float acc = 0.f;
        for (int m = 0; m < HDIM; ++m) acc += w1[k * HDIM + m] * wv1[m * HDIM + j];
        ws[e] = w1[e] + gg1 * acc;
    }
    // B1f = b1 + g1*(b1@wv1 + bv1)
    if (t < HDIM) {
        int j = t;
        float s = 0.f;
        for (int m = 0; m < HDIM; ++m) s += b1[m] * wv1[m * HDIM + j];
        ws[2048 + j] = b1[j] + gg1 * (s + bv1[j]);
    }
    // W2f = w2 + g2*(w2@wv2)   [32x32]
    for (int e = t; e < HDIM * HDIM; e += 256) {
        int k = e >> 5, j = e & 31;
        float acc = 0.f;
        for (int m = 0; m < HDIM; ++m) acc += w2[k * HDIM + m] * wv2[m * HDIM + j];
        ws[2080 + e] = w2[e] + gg2 * acc;
    }
    // B2f
    if (t < HDIM) {
        int j = t;
        float s = 0.f;
        for (int m = 0; m < HDIM; ++m) s += b2[m] * wv2[m * HDIM + j];
        ws[3104 + j] = b2[j] + gg2 * (s + bv2[j]);
    }
}

#define CST 18  // LDS chunk row stride in floats (16 data + 2 pad): 2-way bank aliasing = free

__global__ __launch_bounds__(256)
__attribute__((amdgpu_waves_per_eu(8)))
void mlp_main(
    const float* __restrict__ x,
    const float* __restrict__ ws,
    const float* __restrict__ ln1g, const float* __restrict__ ln1b,
    const float* __restrict__ ln2g, const float* __restrict__ ln2b,
    const float* __restrict__ wo,   const float* __restrict__ bo,
    float* __restrict__ out)
{
    __shared__ float tile[256 * CST];   // 18432 B -> 8 blocks/CU

    const int t = threadIdx.x;
    const size_t rowbase = (size_t)blockIdx.x * 256;

    const v2f* __restrict__ W1v = (const v2f*)ws;                // [64][16] v2f
    const v2f* __restrict__ B1v = (const v2f*)(ws + 2048);       // [16]
    const v2f* __restrict__ W2v = (const v2f*)(ws + 2080);       // [32][16]
    const v2f* __restrict__ B2v = (const v2f*)(ws + 3104);       // [16]
    const v2f* __restrict__ WoV = (const v2f*)wo;                // [32][32] v2f (k-major, 64 j's)
    const v2f* __restrict__ BoV = (const v2f*)bo;                // [32]
    const v2f* __restrict__ G1  = (const v2f*)ln1g;
    const v2f* __restrict__ Bt1 = (const v2f*)ln1b;
    const v2f* __restrict__ G2  = (const v2f*)ln2g;
    const v2f* __restrict__ Bt2 = (const v2f*)ln2b;

    // coalesced-copy lane mapping: 4 lanes cover 64 contiguous bytes of one row,
    // wave covers 16 rows per instruction; s-iterations step 64 rows.
    const int lr = t >> 2;            // staged row this lane copies
    const int lc = (t & 3) * 4;       // float offset within the 16-col chunk... (x4 floats)
    const float* __restrict__ xcpy = x + (rowbase + lr) * 64 + lc;
    float* __restrict__ ocpy = out + (rowbase + lr) * 64 + lc;
    float* __restrict__ lcpy = &tile[lr * CST + lc];
    const float* __restrict__ lrow = &tile[t * CST];   // this thread's own row segment

    // ---------- GEMV1: h1 = x @ W1f + B1f  (K=64, 4 staged chunks of 16 k) ----------
    v2f h1[16];
#pragma unroll
    for (int j = 0; j < 16; ++j) h1[j] = B1v[j];

#pragma unroll 1
    for (int c = 0; c < 4; ++c) {
        // stage: cols 16c..16c+15 of 256 rows, fully coalesced
#pragma unroll
        for (int s = 0; s < 4; ++s) {
            float4 v = *(const float4*)(xcpy + c * 16 + s * (64 * 64));
            v2f* d = (v2f*)(lcpy + s * (64 * CST));
            d[0] = (v2f){ v.x, v.y };
            d[1] = (v2f){ v.z, v.w };
        }
        __syncthreads();
        v2f q[8];
#pragma unroll
        for (int j = 0; j < 8; ++j) q[j] = *(const v2f*)(lrow + 2 * j);
        const v2f* __restrict__ wb = W1v + c * 256;   // 16 k's x 16 v2f
#pragma unroll
        for (int kk = 0; kk < 8; ++kk) {
            const v2f xx = { q[kk].x, q[kk].x };
            const v2f yy = { q[kk].y, q[kk].y };
#pragma unroll
            for (int j = 0; j < 16; ++j)
                h1[j] = h1[j] + xx * wb[(2 * kk) * 16 + j];      // -> v_pk_fma_f32
#pragma unroll
            for (int j = 0; j < 16; ++j)
                h1[j] = h1[j] + yy * wb[(2 * kk + 1) * 16 + j];
        }
        __syncthreads();   // all reads done before next chunk overwrites
    }

    // ---------- LN1 + leaky ----------
    {
        v2f s = { 0.f, 0.f };
#pragma unroll
        for (int j = 0; j < 16; ++j) s = s + h1[j];
        const float m = (s.x + s.y) * (1.f / HDIM);
        const v2f mm = { m, m };
        v2f vs = { 0.f, 0.f };
#pragma unroll
        for (int j = 0; j < 16; ++j) { v2f tt = h1[j] - mm; vs = vs + tt * tt; }
        const float rs = rsqrtf((vs.x + vs.y) * (1.f / HDIM) + EPS);
        const v2f rsv = { rs, rs };
#pragma unroll
        for (int j = 0; j < 16; ++j) {
            v2f a = (h1[j] - mm) * rsv * G1[j] + Bt1[j];
            a.x = fmaxf(a.x, SLOPE * a.x);
            a.y = fmaxf(a.y, SLOPE * a.y);
            h1[j] = a;
        }
    }

    // ---------- GEMV2: h2 = h1 @ W2f + B2f  (32x32) ----------
    v2f h2[16];
#pragma unroll
    for (int j = 0; j < 16; ++j) h2[j] = B2v[j];
#pragma unroll
    for (int i = 0; i < 16; ++i) {
        const v2f hx = { h1[i].x, h1[i].x };
        const v2f hy = { h1[i].y, h1[i].y };
        const v2f* __restrict__ w0 = W2v + (2 * i) * 16;
        const v2f* __restrict__ w1r = W2v + (2 * i + 1) * 16;
#pragma unroll
        for (int j = 0; j < 16; ++j) h2[j] = h2[j] + hx * w0[j];
#pragma unroll
        for (int j = 0; j < 16; ++j) h2[j] = h2[j] + hy * w1r[j];
    }

    // ---------- LN2 + leaky ----------
    {
        v2f s = { 0.f, 0.f };
#pragma unroll
        for (int j = 0; j < 16; ++j) s = s + h2[j];
        const float m = (s.x + s.y) * (1.f / HDIM);
        const v2f mm = { m, m };
        v2f vs = { 0.f, 0.f };
#pragma unroll
        for (int j = 0; j < 16; ++j) { v2f tt = h2[j] - mm; vs = vs + tt * tt; }
        const float rs = rsqrtf((vs.x + vs.y) * (1.f / HDIM) + EPS);
        const v2f rsv = { rs, rs };
#pragma unroll
        for (int j = 0; j < 16; ++j) {
            v2f a = (h2[j] - mm) * rsv * G2[j] + Bt2[j];
            a.x = fmaxf(a.x, SLOPE * a.x);
            a.y = fmaxf(a.y, SLOPE * a.y);
            h2[j] = a;
        }
    }

    // ---------- GEMV3: out = h2 @ wo + bo  (K=32, N=64; 4 staged chunks of 16 j) ----------
    // tile buffer is free here: last GEMV1 barrier guaranteed all reads retired.
#pragma unroll 1
    for (int c = 0; c < 4; ++c) {
        v2f acc[8];
#pragma unroll
        for (int j = 0; j < 8; ++j) acc[j] = BoV[c * 8 + j];
#pragma unroll
        for (int i = 0; i < 16; ++i) {
            const v2f hx = { h2[i].x, h2[i].x };
            const v2f hy = { h2[i].y, h2[i].y };
            const v2f* __restrict__ w0 = WoV + (2 * i) * 32 + c * 8;
            const v2f* __restrict__ w1r = WoV + (2 * i + 1) * 32 + c * 8;
#pragma unroll
            for (int j = 0; j < 8; ++j) acc[j] = acc[j] + hx * w0[j];
#pragma unroll
            for (int j = 0; j < 8; ++j) acc[j] = acc[j] + hy * w1r[j];
        }
        // own-row chunk -> LDS (2-way aliasing, free)
        v2f* lw = (v2f*)lrow;
#pragma unroll
        for (int j = 0; j < 8; ++j) lw[j] = acc[j];
        __syncthreads();
        // coalesced store: 16 rows x 64 contiguous bytes per wave-instr
#pragma unroll
        for (int s = 0; s < 4; ++s) {
            const v2f* rsrc = (const v2f*)(lcpy + s * (64 * CST));
            v2f a = rsrc[0];
            v2f b = rsrc[1];
            float4 v = { a.x, a.y, b.x, b.y };
            *(float4*)(ocpy + c * 16 + s * (64 * 64)) = v;
        }
        __syncthreads();   // store-reads retired before next chunk overwrites
    }
}

extern "C" void kernel_launch(void* const* d_in, const int* in_sizes, int n_in,
                              void* d_out, int out_size, void* d_ws, size_t ws_size,
                              hipStream_t stream) {
    const float* x    = (const float*)d_in[0];
    const float* w1   = (const float*)d_in[1];
    const float* b1   = (const float*)d_in[2];
    // d_in[3..6] = wq1,bq1,wk1,bk1 : dead (softmax over T=1 is identically 1)
    const float* wv1  = (const float*)d_in[7];
    const float* bv1  = (const float*)d_in[8];
    const float* g1   = (const float*)d_in[9];
    const float* ln1g = (const float*)d_in[10];
    const float* ln1b = (const float*)d_in[11];
    const float* w2   = (const float*)d_in[12];
    const float* b2   = (const float*)d_in[13];
    // d_in[14..17] dead
    const float* wv2  = (const float*)d_in[18];
    const float* bv2  = (const float*)d_in[19];
    const float* g2   = (const float*)d_in[20];
    const float* ln2g = (const float*)d_in[21];
    const float* ln2b = (const float*)d_in[22];
    const float* wo   = (const float*)d_in[23];
    const float* bo   = (const float*)d_in[24];

    float* ws = (float*)d_ws;
    float* out = (float*)d_out;

    const int rows = in_sizes[0] / 64;     // 1,048,576

    mlp_preproc<<<1, 256, 0, stream>>>(w1, b1, wv1, bv1, g1,
                                       w2, b2, wv2, bv2, g2, ws);

    mlp_main<<<rows / 256, 256, 0, stream>>>(x, ws, ln1g, ln1b, ln2g, ln2b,
                                             wo, bo, out);
}

// Round 2
// 689.772 us; speedup vs baseline: 1.3496x; 1.3496x over previous
//
#include <hip/hip_runtime.h>

// MlpWithAttention: B=2^20 rows, in=64, H=32, out=64, fp32.
// Attention over T=1 => softmax==1 => affine fold: h <- h@(I+g*wv) + g*bv,
// folded into the preceding Linear (preproc). Main kernel: one thread = one row.
// v3: single-pass LDS transpose staging. Whole 256-row x-tile (64 KB, contiguous)
// loaded in ONE coalesced burst -> LDS[256][66] (stride-66 = bank-optimal for v2f)
// -> per-thread row compute -> output tile written back to LDS -> ONE coalesced
// store burst. Global bytes touched exactly once (no cross-pass L2 thrash, the
// round-1 mistake). 2 barriers/block total. 67.6 KB LDS -> 2 blocks/CU.

#define HDIM 32
#define EPS 1e-5f
#define SLOPE 0.01f
#define STR 66   // LDS row stride in floats: bank = (2t + k) % 32 -> optimal 4/bank for b64

typedef float v2f __attribute__((ext_vector_type(2)));

// ws layout (floats):
//   0    .. 2048 : W1f[64][32]  (k-major, j contiguous)
//   2048 .. 2080 : B1f[32]
//   2080 .. 3104 : W2f[32][32]  (k-major)
//   3104 .. 3136 : B2f[32]

__global__ void mlp_preproc(
    const float* __restrict__ w1, const float* __restrict__ b1,
    const float* __restrict__ wv1, const float* __restrict__ bv1,
    const float* __restrict__ g1,
    const float* __restrict__ w2, const float* __restrict__ b2,
    const float* __restrict__ wv2, const float* __restrict__ bv2,
    const float* __restrict__ g2,
    float* __restrict__ ws)
{
    const int t = threadIdx.x;  // one block, 256 threads
    const float gg1 = g1[0], gg2 = g2[0];

    // W1f = w1 + g1*(w1@wv1)   [64x32]
    for (int e = t; e < 64 * HDIM; e += 256) {
        int k = e >> 5, j = e & 31;
        float acc = 0.f;
        for (int m = 0; m < HDIM; ++m) acc += w1[k * HDIM + m] * wv1[m * HDIM + j];
        ws[e] = w1[e] + gg1 * acc;
    }
    // B1f = b1 + g1*(b1@wv1 + bv1)
    if (t < HDIM) {
        int j = t;
        float s = 0.f;
        for (int m = 0; m < HDIM; ++m) s += b1[m] * wv1[m * HDIM + j];
        ws[2048 + j] = b1[j] + gg1 * (s + bv1[j]);
    }
    // W2f = w2 + g2*(w2@wv2)   [32x32]
    for (int e = t; e < HDIM * HDIM; e += 256) {
        int k = e >> 5, j = e & 31;
        float acc = 0.f;
        for (int m = 0; m < HDIM; ++m) acc += w2[k * HDIM + m] * wv2[m * HDIM + j];
        ws[2080 + e] = w2[e] + gg2 * acc;
    }
    // B2f
    if (t < HDIM) {
        int j = t;
        float s = 0.f;
        for (int m = 0; m < HDIM; ++m) s += b2[m] * wv2[m * HDIM + j];
        ws[3104 + j] = b2[j] + gg2 * (s + bv2[j]);
    }
}

__global__ __launch_bounds__(256)
void mlp_main(
    const float* __restrict__ x,
    const float* __restrict__ ws,
    const float* __restrict__ ln1g, const float* __restrict__ ln1b,
    const float* __restrict__ ln2g, const float* __restrict__ ln2b,
    const float* __restrict__ wo,   const float* __restrict__ bo,
    float* __restrict__ out)
{
    __shared__ float tile[256 * STR];   // 67584 B -> 2 blocks/CU

    const int t = threadIdx.x;
    const size_t rowbase = (size_t)blockIdx.x * 256;

    const v2f* __restrict__ W1v = (const v2f*)ws;                // [64][16] v2f
    const v2f* __restrict__ B1v = (const v2f*)(ws + 2048);       // [16]
    const v2f* __restrict__ W2v = (const v2f*)(ws + 2080);       // [32][16]
    const v2f* __restrict__ B2v = (const v2f*)(ws + 3104);       // [16]
    const v2f* __restrict__ WoV = (const v2f*)wo;                // [32][32] v2f (k-major, 64 j's)
    const v2f* __restrict__ BoV = (const v2f*)bo;                // [32]
    const v2f* __restrict__ G1  = (const v2f*)ln1g;
    const v2f* __restrict__ Bt1 = (const v2f*)ln1b;
    const v2f* __restrict__ G2  = (const v2f*)ln2g;
    const v2f* __restrict__ Bt2 = (const v2f*)ln2b;

    // copy mapping: float4 index g4 = i*256 + t covers the 64-KB tile linearly.
    // row = g4>>4 = 16i + (t>>4), col = 4*(g4&15) = 4*(t&15)  (both per-thread const).
    const int ca = t >> 4;               // row sub-index within a 16-row stripe
    const int cc = (t & 15) * 4;         // float column of this thread's float4
    float* __restrict__ lstage = &tile[ca * STR + cc];
    const float4* __restrict__ xr4 = (const float4*)(x + rowbase * 64);
    float4* __restrict__ or4       = (float4*)(out + rowbase * 64);

    // ---------- stage-in: one coalesced pass over the whole tile ----------
#pragma unroll
    for (int i = 0; i < 16; ++i) {
        float4 v = xr4[i * 256 + t];
        float* d = lstage + i * (16 * STR);
        *(v2f*)(d)     = (v2f){ v.x, v.y };
        *(v2f*)(d + 2) = (v2f){ v.z, v.w };
    }
    __syncthreads();

    const float* __restrict__ lrow = &tile[t * STR];   // this thread's own row

    // ---------- GEMV1: h1 = x @ W1f + B1f  (K=64, 4 chunks of 16 from LDS) ----------
    v2f h1[16];
#pragma unroll
    for (int j = 0; j < 16; ++j) h1[j] = B1v[j];

#pragma unroll 1
    for (int c = 0; c < 4; ++c) {
        v2f q[8];
#pragma unroll
        for (int j = 0; j < 8; ++j) q[j] = *(const v2f*)(lrow + c * 16 + 2 * j);
        const v2f* __restrict__ wb = W1v + c * 256;   // 16 k's x 16 v2f
#pragma unroll
        for (int kk = 0; kk < 8; ++kk) {
            const v2f xx = { q[kk].x, q[kk].x };
            const v2f yy = { q[kk].y, q[kk].y };
#pragma unroll
            for (int j = 0; j < 16; ++j)
                h1[j] = h1[j] + xx * wb[(2 * kk) * 16 + j];      // -> v_pk_fma_f32
#pragma unroll
            for (int j = 0; j < 16; ++j)
                h1[j] = h1[j] + yy * wb[(2 * kk + 1) * 16 + j];
        }
    }

    // ---------- LN1 + leaky ----------
    {
        v2f s = { 0.f, 0.f };
#pragma unroll
        for (int j = 0; j < 16; ++j) s = s + h1[j];
        const float m = (s.x + s.y) * (1.f / HDIM);
        const v2f mm = { m, m };
        v2f vs = { 0.f, 0.f };
#pragma unroll
        for (int j = 0; j < 16; ++j) { v2f tt = h1[j] - mm; vs = vs + tt * tt; }
        const float rs = rsqrtf((vs.x + vs.y) * (1.f / HDIM) + EPS);
        const v2f rsv = { rs, rs };
#pragma unroll
        for (int j = 0; j < 16; ++j) {
            v2f a = (h1[j] - mm) * rsv * G1[j] + Bt1[j];
            a.x = fmaxf(a.x, SLOPE * a.x);
            a.y = fmaxf(a.y, SLOPE * a.y);
            h1[j] = a;
        }
    }

    // ---------- GEMV2: h2 = h1 @ W2f + B2f  (32x32) ----------
    v2f h2[16];
#pragma unroll
    for (int j = 0; j < 16; ++j) h2[j] = B2v[j];
#pragma unroll
    for (int i = 0; i < 16; ++i) {
        const v2f hx = { h1[i].x, h1[i].x };
        const v2f hy = { h1[i].y, h1[i].y };
        const v2f* __restrict__ w0 = W2v + (2 * i) * 16;
        const v2f* __restrict__ w1r = W2v + (2 * i + 1) * 16;
#pragma unroll
        for (int j = 0; j < 16; ++j) h2[j] = h2[j] + hx * w0[j];
#pragma unroll
        for (int j = 0; j < 16; ++j) h2[j] = h2[j] + hy * w1r[j];
    }

    // ---------- LN2 + leaky ----------
    {
        v2f s = { 0.f, 0.f };
#pragma unroll
        for (int j = 0; j < 16; ++j) s = s + h2[j];
        const float m = (s.x + s.y) * (1.f / HDIM);
        const v2f mm = { m, m };
        v2f vs = { 0.f, 0.f };
#pragma unroll
        for (int j = 0; j < 16; ++j) { v2f tt = h2[j] - mm; vs = vs + tt * tt; }
        const float rs = rsqrtf((vs.x + vs.y) * (1.f / HDIM) + EPS);
        const v2f rsv = { rs, rs };
#pragma unroll
        for (int j = 0; j < 16; ++j) {
            v2f a = (h2[j] - mm) * rsv * G2[j] + Bt2[j];
            a.x = fmaxf(a.x, SLOPE * a.x);
            a.y = fmaxf(a.y, SLOPE * a.y);
            h2[j] = a;
        }
    }

    // ---------- GEMV3: out = h2 @ wo + bo (K=32, N=64) -> own LDS row ----------
    // Row ownership: thread t read only row t (GEMV1) and writes only row t here,
    // so no barrier is needed between GEMV1 and these writes.
    float* __restrict__ lwrow = &tile[t * STR];
#pragma unroll 1
    for (int c = 0; c < 4; ++c) {
        v2f acc[8];
#pragma unroll
        for (int j = 0; j < 8; ++j) acc[j] = BoV[c * 8 + j];
#pragma unroll
        for (int i = 0; i < 16; ++i) {
            const v2f hx = { h2[i].x, h2[i].x };
            const v2f hy = { h2[i].y, h2[i].y };
            const v2f* __restrict__ w0 = WoV + (2 * i) * 32 + c * 8;
            const v2f* __restrict__ w1r = WoV + (2 * i + 1) * 32 + c * 8;
#pragma unroll
            for (int j = 0; j < 8; ++j) acc[j] = acc[j] + hx * w0[j];
#pragma unroll
            for (int j = 0; j < 8; ++j) acc[j] = acc[j] + hy * w1r[j];
        }
        float* lw = lwrow + c * 16;
#pragma unroll
        for (int j = 0; j < 8; ++j) *(v2f*)(lw + 2 * j) = acc[j];
    }
    __syncthreads();

    // ---------- store-out: one coalesced pass over the whole tile ----------
#pragma unroll
    for (int i = 0; i < 16; ++i) {
        const float* s = lstage + i * (16 * STR);
        v2f p0 = *(const v2f*)(s);
        v2f p1 = *(const v2f*)(s + 2);
        or4[i * 256 + t] = (float4){ p0.x, p0.y, p1.x, p1.y };
    }
}

extern "C" void kernel_launch(void* const* d_in, const int* in_sizes, int n_in,
                              void* d_out, int out_size, void* d_ws, size_t ws_size,
                              hipStream_t stream) {
    const float* x    = (const float*)d_in[0];
    const float* w1   = (const float*)d_in[1];
    const float* b1   = (const float*)d_in[2];
    // d_in[3..6] = wq1,bq1,wk1,bk1 : dead (softmax over T=1 is identically 1)
    const float* wv1  = (const float*)d_in[7];
    const float* bv1  = (const float*)d_in[8];
    const float* g1   = (const float*)d_in[9];
    const float* ln1g = (const float*)d_in[10];
    const float* ln1b = (const float*)d_in[11];
    const float* w2   = (const float*)d_in[12];
    const float* b2   = (const float*)d_in[13];
    // d_in[14..17] dead
    const float* wv2  = (const float*)d_in[18];
    const float* bv2  = (const float*)d_in[19];
    const float* g2   = (const float*)d_in[20];
    const float* ln2g = (const float*)d_in[21];
    const float* ln2b = (const float*)d_in[22];
    const float* wo   = (const float*)d_in[23];
    const float* bo   = (const float*)d_in[24];

    float* ws = (float*)d_ws;
    float* out = (float*)d_out;

    const int rows = in_sizes[0] / 64;     // 1,048,576

    mlp_preproc<<<1, 256, 0, stream>>>(w1, b1, wv1, bv1, g1,
                                       w2, b2, wv2, bv2, g2, ws);

    mlp_main<<<rows / 256, 256, 0, stream>>>(x, ws, ln1g, ln1b, ln2g, ln2b,
                                             wo, bo, out);
}